// Round 10
// baseline (220.521 us; speedup 1.0000x reference)
//
#include <hip/hip_runtime.h>

#define BATCH 4
#define CH    256
#define DQ    32
#define NPIX  4096
#define LOG2E 1.4426950408889634f

typedef unsigned short u16;
typedef unsigned int   u32;
typedef __attribute__((ext_vector_type(8))) short short8;
typedef __attribute__((ext_vector_type(16))) float f32x16;

#if defined(__has_builtin)
#if __has_builtin(__builtin_amdgcn_exp2f)
#define EXP2F(x) __builtin_amdgcn_exp2f(x)
#else
#define EXP2F(x) __expf((x) * 0.6931471805599453f)
#endif
#else
#define EXP2F(x) __expf((x) * 0.6931471805599453f)
#endif

__device__ __forceinline__ float b2f(u32 u) {
  union { u32 i; float f; } v; v.i = (u & 0xffffu) << 16; return v.f;
}
__device__ __forceinline__ u16 f2b(float f) {            // RNE fp32->bf16
  union { float f; u32 i; } v; v.f = f;
  u32 x = v.i; x += 0x7fffu + ((x >> 16) & 1u);
  return (u16)(x >> 16);
}
__device__ __forceinline__ u32 pack_hi16(float lo, float hi) {
  union { float f; u32 i; } a, b; a.f = lo; b.f = hi;
  return __builtin_amdgcn_perm(b.i, a.i, 0x07060302u);
}

// ---------------------------------------------------------------------------
// wconv: pre-swizzle W into 32x32x16 A-frag order (unchanged from r9).
// ---------------------------------------------------------------------------
__global__ __launch_bounds__(256) void wconv(
    const float* __restrict__ Wq, const float* __restrict__ Wk,
    const float* __restrict__ Wv, u16* __restrict__ wsz, u16* __restrict__ wsz_lo)
{
  const int blk = blockIdx.x;
  const int jt = blk >> 4, kk = blk & 15;
  #pragma unroll
  for (int rep = 0; rep < 2; ++rep) {
    const int idx = rep * 256 + threadIdx.x;
    const int j = idx >> 4, el = idx & 15, e = kk * 16 + el;
    const float* Wsrc = (jt == 0) ? Wq : (jt == 1) ? Wk : Wv;
    const int row = (jt <= 1) ? j : (jt - 2) * 32 + j;
    float v = Wsrc[(size_t)row * CH + e];
    if (jt == 0) v *= LOG2E;
    const u16 hi = f2b(v);
    const int o = (((jt * 16 + kk) * 2 + (el >> 3)) * 32 + j) * 8 + (el & 7);
    wsz[o] = hi;
    if (jt < 2) wsz_lo[o] = f2b(v - b2f(hi));
  }
}

// ---------------------------------------------------------------------------
// proj v2 (unchanged from r9): one block per (32-pixel tile, b), x staged
// once as hi/lo bf16 in LDS; w0->q, w1->k, w2/w3 -> Wv tiles.
// ---------------------------------------------------------------------------
__global__ __launch_bounds__(256) void proj(
    const float* __restrict__ x,
    const u16* __restrict__ wsz, const u16* __restrict__ wsz_lo,
    const float* __restrict__ bq, const float* __restrict__ bk, const float* __restrict__ bv,
    u16* __restrict__ q_t, u16* __restrict__ k_t, u16* __restrict__ v_swz)
{
  const int nt = blockIdx.x, b = blockIdx.y;
  const int n0 = nt * 32;
  const int t = threadIdx.x;
  const int w = t >> 6, hl = (t >> 5) & 1, l31 = t & 31;

  __shared__ __align__(16) u16 xh[32 * 264];
  __shared__ __align__(16) u16 xl[32 * 264];

  #pragma unroll
  for (int p = 0; p < 8; ++p) {
    const int e = p * 32 + (t >> 3), n4 = (t & 7) * 4;
    const float4 v4 = *(const float4*)&x[((size_t)b * CH + e) * NPIX + n0 + n4];
    const float vv[4] = {v4.x, v4.y, v4.z, v4.w};
    #pragma unroll
    for (int jj = 0; jj < 4; ++jj) {
      const u16 hi = f2b(vv[jj]);
      xh[(n4 + jj) * 264 + e] = hi;
      xl[(n4 + jj) * 264 + e] = f2b(vv[jj] - b2f(hi));
    }
  }
  __syncthreads();

  const int n = n0 + l31;

  if (w <= 1) {
    const int jt = w;
    f32x16 a0, a1, a2;
    #pragma unroll
    for (int r = 0; r < 16; ++r) { a0[r] = 0.f; a1[r] = 0.f; a2[r] = 0.f; }
    #pragma unroll
    for (int kk = 0; kk < 16; ++kk) {
      const int wo = ((jt * 16 + kk) * 2 + hl) * 256 + l31 * 8;
      const short8 Ah = *(const short8*)&wsz[wo];
      const short8 Al = *(const short8*)&wsz_lo[wo];
      const int xo = l31 * 264 + kk * 16 + hl * 8;
      const short8 Bh = *(const short8*)&xh[xo];
      const short8 Bl = *(const short8*)&xl[xo];
      a0 = __builtin_amdgcn_mfma_f32_32x32x16_bf16(Ah, Bh, a0, 0, 0, 0);
      a1 = __builtin_amdgcn_mfma_f32_32x32x16_bf16(Ah, Bl, a1, 0, 0, 0);
      a2 = __builtin_amdgcn_mfma_f32_32x32x16_bf16(Al, Bh, a2, 0, 0, 0);
    }
    u16* dst = (jt == 0) ? q_t : k_t;
    const float* bias = (jt == 0) ? bq : bk;
    const float bscale = (jt == 0) ? LOG2E : 1.0f;
    #pragma unroll
    for (int r = 0; r < 16; ++r) {
      const int d = (r & 3) + 8 * (r >> 2) + 4 * hl;
      dst[((size_t)b * NPIX + n) * DQ + d] =
        f2b((a0[r] + a1[r]) + (a2[r] + bias[d] * bscale));
    }
  } else {
    #pragma unroll
    for (int ci = 0; ci < 4; ++ci) {
      const int ctv = (w - 2) * 4 + ci;
      const int jt = 2 + ctv;
      f32x16 a0, a1;
      #pragma unroll
      for (int r = 0; r < 16; ++r) { a0[r] = 0.f; a1[r] = 0.f; }
      #pragma unroll
      for (int kk = 0; kk < 16; kk += 2) {
        const short8 Ah0 = *(const short8*)&wsz[((jt * 16 + kk) * 2 + hl) * 256 + l31 * 8];
        const short8 Bh0 = *(const short8*)&xh[l31 * 264 + kk * 16 + hl * 8];
        const short8 Ah1 = *(const short8*)&wsz[((jt * 16 + kk + 1) * 2 + hl) * 256 + l31 * 8];
        const short8 Bh1 = *(const short8*)&xh[l31 * 264 + (kk + 1) * 16 + hl * 8];
        a0 = __builtin_amdgcn_mfma_f32_32x32x16_bf16(Ah0, Bh0, a0, 0, 0, 0);
        a1 = __builtin_amdgcn_mfma_f32_32x32x16_bf16(Ah1, Bh1, a1, 0, 0, 0);
      }
      const int kc = (l31 >> 4) & 1, h3 = (l31 >> 3) & 1, j8 = l31 & 7;
      u16* dst = v_swz + (((((size_t)b * 128 + nt) * 8 + ctv) * 2 + kc) * 2 + h3) * 256 + j8;
      #pragma unroll
      for (int r = 0; r < 16; ++r) {
        const int c5 = (r & 3) + 8 * (r >> 2) + 4 * hl;
        dst[c5 * 8] = f2b(a0[r] + a1[r] + bv[ctv * 32 + c5]);
      }
    }
  }
}

// ---------------------------------------------------------------------------
// attn r10.  Grid 256 (1D, XCD-pinned: b = (blk&7)>>1 so each XCD's L2 holds
// ONE batch's 2 MB V).  Block 512 thr = 8 waves = nt(2: which 32-n) x
// ch(4: 64-channel slice).  acc[2] = 32 AGPR/wave -> ~140 regs/thread,
// safely under the 131072/512 = 256 regs/thread per-block HW cap (the r6-r9
// spill: acc[8]=128 forced arch cap 128).
// Per 32-m chunk: V staged once to double-buffered LDS (global_load_lds,
// shared by all 8 waves); 4 semi-owner waves (one per SIMD: (nt, ch=nt) and
// (nt, ch=nt+2)) compute S^T + exp for 16 rows each (exp exactly once),
// publish P B-frags via LDS; everyone does PV from LDS.  One barrier/iter.
// No m-split -> no end combine.  Epilogue: out = gamma*y/l + x.
// ---------------------------------------------------------------------------
struct PHalf { u32 p00, p01, p10, p11; };

template <int H>
__device__ __forceinline__ void compute_p_half(
    const short8 kf0, const short8 kf1, const short8 qf0, const short8 qf1,
    const int hl, const int lane, float& lrun, u16* __restrict__ pdst)
{
  f32x16 st;
  #pragma unroll
  for (int r = 0; r < 16; ++r) st[r] = 0.f;
  st = __builtin_amdgcn_mfma_f32_32x32x16_bf16(kf0, qf0, st, 0, 0, 0);
  st = __builtin_amdgcn_mfma_f32_32x32x16_bf16(kf1, qf1, st, 0, 0, 0);
  const float e0 = EXP2F(st[8 * H + 0]);
  const float e1 = EXP2F(st[8 * H + 1]);
  const float e2 = EXP2F(st[8 * H + 2]);
  const float e3 = EXP2F(st[8 * H + 3]);
  const float e4 = EXP2F(st[8 * H + 4]);
  const float e5 = EXP2F(st[8 * H + 5]);
  const float e6 = EXP2F(st[8 * H + 6]);
  const float e7 = EXP2F(st[8 * H + 7]);
  lrun += ((e0 + e1) + (e2 + e3)) + ((e4 + e5) + (e6 + e7));
  const u32 p00 = pack_hi16(e0, e1), p01 = pack_hi16(e2, e3);
  const u32 p10 = pack_hi16(e4, e5), p11 = pack_hi16(e6, e7);
  // C-layout -> B-operand (kc = H), r5-verified shfl transform
  const u32 s0 = hl ? p00 : p10;
  const u32 s1 = hl ? p01 : p11;
  const u32 r0 = (u32)__shfl_xor((int)s0, 32);
  const u32 r1 = (u32)__shfl_xor((int)s1, 32);
  uint4 bu;
  bu.x = hl ? r0 : p00;
  bu.y = hl ? r1 : p01;
  bu.z = hl ? p10 : r0;
  bu.w = hl ? p11 : r1;
  *(uint4*)(pdst + lane * 8) = bu;
}

__global__ __launch_bounds__(512) void attn(
    const u16* __restrict__ q_t, const u16* __restrict__ k_t,
    const u16* __restrict__ v_swz, const float* __restrict__ x,
    const float* __restrict__ gamma, float* __restrict__ out)
{
  const int blk = blockIdx.x;
  const int b = (blk & 7) >> 1;                      // XCD-pinned batch
  const int tile = ((blk >> 3) << 1) | (blk & 1);    // 0..63
  const int n0 = tile * 64;
  const int t = threadIdx.x;
  const int w = t >> 6, lane = t & 63, hl = lane >> 5, l31 = lane & 31;
  const int nt = w >> 2, ch = w & 3;
  // semi-owner role: (nt, ch=nt) -> h0, (nt, ch=nt+2) -> h1, else -1
  const int dch = ch - nt;
  const int hrole = (dch == 0) ? 0 : (dch == 2) ? 1 : -1;

  __shared__ __align__(16) u16 vlds[2][8192];        // 32 KB  [buf][chunk swz]
  __shared__ __align__(16) u16 plds[2][2][2][512];   // 8 KB   [buf][nt][kc][lane*8]
  __shared__ float lbufs[2][2][32];                  // [nt][h][n]

  const u16* kb = k_t + (size_t)b * NPIX * DQ;
  const u16* vbase = v_swz + (size_t)b * 128 * 8192;

  // Q B-frags for this wave's nt (only owners consume)
  short8 qf0{}, qf1{};
  if (hrole >= 0) {
    const u16* qp = q_t + ((size_t)b * NPIX + n0 + nt * 32 + l31) * DQ + hl * 8;
    qf0 = *(const short8*)(qp);
    qf1 = *(const short8*)(qp + 16);
  }

  f32x16 acc[2];
  #pragma unroll
  for (int a = 0; a < 2; ++a)
    #pragma unroll
    for (int r = 0; r < 16; ++r) acc[a][r] = 0.f;
  float lrun = 0.f;

  auto stageV = [&](int mc, int buf) {
    const u16* src = vbase + (size_t)mc * 8192;
    #pragma unroll
    for (int s = 0; s < 2; ++s) {
      const int off = (w * 2 + s) * 512 + lane * 8;  // u16 elems, lane*16 B
      __builtin_amdgcn_global_load_lds(
          (const __attribute__((address_space(1))) void*)(src + off),
          (__attribute__((address_space(3))) void*)(&vlds[buf][off]), 16, 0, 0);
    }
  };

  // ---- prologue: chunk 0 ----
  stageV(0, 0);
  if (hrole >= 0) {
    const u16* kp = kb + (size_t)l31 * DQ + hl * 8;
    const short8 kf0 = *(const short8*)(kp);
    const short8 kf1 = *(const short8*)(kp + 16);
    if (hrole == 0) compute_p_half<0>(kf0, kf1, qf0, qf1, hl, lane, lrun, &plds[0][nt][0][0]);
    else            compute_p_half<1>(kf0, kf1, qf0, qf1, hl, lane, lrun, &plds[0][nt][1][0]);
  }
  __syncthreads();

  for (int cc = 0; cc < 128; ++cc) {
    const int buf = cc & 1;
    short8 kf0{}, kf1{};
    if (cc < 127) {
      stageV(cc + 1, buf ^ 1);
      if (hrole >= 0) {
        const u16* kp = kb + (size_t)((cc + 1) * 32 + l31) * DQ + hl * 8;
        kf0 = *(const short8*)(kp);
        kf1 = *(const short8*)(kp + 16);
      }
    }

    // ---- PV from LDS: acc[ct2] += V^T(A) . P^T(B) ----
    union { uint4 u; short8 s; } pf[2];
    pf[0].u = *(const uint4*)&plds[buf][nt][0][lane * 8];
    pf[1].u = *(const uint4*)&plds[buf][nt][1][lane * 8];
    #pragma unroll
    for (int ct2 = 0; ct2 < 2; ++ct2) {
      const int ct = ch * 2 + ct2;
      #pragma unroll
      for (int kc = 0; kc < 2; ++kc) {
        const short8 av = *(const short8*)&vlds[buf][((ct * 2 + kc) * 2 + hl) * 256 + l31 * 8];
        acc[ct2] = __builtin_amdgcn_mfma_f32_32x32x16_bf16(av, pf[kc].s, acc[ct2], 0, 0, 0);
      }
    }

    // ---- semi-owners compute P for chunk cc+1 into buf^1 ----
    if (cc < 127 && hrole >= 0) {
      if (hrole == 0) compute_p_half<0>(kf0, kf1, qf0, qf1, hl, lane, lrun, &plds[buf ^ 1][nt][0][0]);
      else            compute_p_half<1>(kf0, kf1, qf0, qf1, hl, lane, lrun, &plds[buf ^ 1][nt][1][0]);
    }
    __syncthreads();   // P visible, V staged (vmcnt drained), vlds[buf] reads done
  }

  // ---- l broadcast ----
  if (hrole >= 0) {
    const float ls = lrun + __shfl_xor(lrun, 32);
    if (hl == 0) lbufs[nt][hrole][l31] = ls;
  }
  __syncthreads();

  // ---- epilogue: every wave writes its 32n x 64c slice ----
  const float l = lbufs[nt][0][l31] + lbufs[nt][1][l31];
  const float linv = 1.0f / l;
  const float g = gamma[0];
  #pragma unroll
  for (int ct2 = 0; ct2 < 2; ++ct2) {
    const int ct = ch * 2 + ct2;
    #pragma unroll
    for (int r = 0; r < 16; ++r) {
      const int c = ct * 32 + (r & 3) + 8 * (r >> 2) + 4 * hl;
      const size_t idx = ((size_t)b * CH + c) * NPIX + n0 + nt * 32 + l31;
      out[idx] = g * acc[ct2][r] * linv + x[idx];
    }
  }
}

// ---------------------------------------------------------------------------
extern "C" void kernel_launch(void* const* d_in, const int* in_sizes, int n_in,
                              void* d_out, int out_size, void* d_ws, size_t ws_size,
                              hipStream_t stream) {
  const float* x  = (const float*)d_in[0];
  const float* Wq = (const float*)d_in[1];
  const float* bq = (const float*)d_in[2];
  const float* Wk = (const float*)d_in[3];
  const float* bk = (const float*)d_in[4];
  const float* Wv = (const float*)d_in[5];
  const float* bv = (const float*)d_in[6];
  const float* gm = (const float*)d_in[7];
  float* out = (float*)d_out;

  const size_t qk_e = (size_t)BATCH * NPIX * DQ;
  const size_t v_e  = (size_t)BATCH * NPIX * CH;
  const size_t w_e  = 10 * 16 * 2 * 32 * 8;
  const size_t wl_e = 2 * 16 * 2 * 32 * 8;
  const size_t need = (2 * qk_e + v_e + w_e + wl_e) * sizeof(u16);
  if (ws_size < need) return;                  // diagnostic: absmax ~6.875

  u16* q_t    = (u16*)d_ws;
  u16* k_t    = q_t + qk_e;
  u16* v_swz  = k_t + qk_e;
  u16* wsz    = v_swz + v_e;
  u16* wsz_lo = wsz + w_e;

  wconv<<<dim3(160), 256, 0, stream>>>(Wq, Wk, Wv, wsz, wsz_lo);
  proj <<<dim3(NPIX / 32, BATCH), 256, 0, stream>>>(x, wsz, wsz_lo, bq, bk, bv, q_t, k_t, v_swz);
  attn <<<dim3(256), 512, 0, stream>>>(q_t, k_t, v_swz, x, gm, out);
}